// Round 2
// baseline (999.475 us; speedup 1.0000x reference)
//
#include <hip/hip_runtime.h>

#define H    64
#define F    256
#define BM   64
#define NSEG 256

// ---------------------------------------------------------------------------
// Kernel 1: fused QKV projection.  q/k/v[n,j] = sum_i x[n,i]*W*[i,j] + b*[j]
// Block = 256 threads, handles BM=64 node rows.  x tile staged in LDS (64KB,
// 2 blocks/CU).  Thread (j = t&63, group mg = t>>6) computes 16 nodes x 3
// outputs = 48 accumulators.  W loads coalesced across j; LDS reads are
// wave-broadcast (conflict-free).
// ---------------------------------------------------------------------------
__global__ __launch_bounds__(256) void qkv_proj(
    const float* __restrict__ x,
    const float* __restrict__ Wq, const float* __restrict__ bq,
    const float* __restrict__ Wk, const float* __restrict__ bk,
    const float* __restrict__ Wv, const float* __restrict__ bv,
    float* __restrict__ q, float* __restrict__ k, float* __restrict__ v,
    int N)
{
    __shared__ float xs[BM][F];
    const int t = threadIdx.x;
    const int block0 = blockIdx.x * BM;
    const int rows = min(BM, N - block0);

    const float4* x4 = (const float4*)(x + (size_t)block0 * F);
    float4* xs4 = (float4*)&xs[0][0];
    #pragma unroll
    for (int it = 0; it < (BM * F / 4) / 256; ++it) {
        int idx = t + it * 256;
        int r = idx >> 6;                       // F/4 = 64 float4 per row
        float4 val = (r < rows) ? x4[idx] : make_float4(0.f, 0.f, 0.f, 0.f);
        xs4[idx] = val;
    }
    __syncthreads();

    const int j  = t & 63;
    const int m0 = (t >> 6) * 16;

    float aq[16], ak[16], av[16];
    const float bqj = bq[j], bkj = bk[j], bvj = bv[j];
    #pragma unroll
    for (int m = 0; m < 16; ++m) { aq[m] = bqj; ak[m] = bkj; av[m] = bvj; }

    for (int i = 0; i < F; i += 4) {
        float wq[4], wk[4], wv[4];
        #pragma unroll
        for (int u = 0; u < 4; ++u) {
            wq[u] = Wq[(i + u) * H + j];
            wk[u] = Wk[(i + u) * H + j];
            wv[u] = Wv[(i + u) * H + j];
        }
        #pragma unroll
        for (int m = 0; m < 16; ++m) {
            const float4 xv = *(const float4*)&xs[m0 + m][i];
            aq[m] += xv.x * wq[0] + xv.y * wq[1] + xv.z * wq[2] + xv.w * wq[3];
            ak[m] += xv.x * wk[0] + xv.y * wk[1] + xv.z * wk[2] + xv.w * wk[3];
            av[m] += xv.x * wv[0] + xv.y * wv[1] + xv.z * wv[2] + xv.w * wv[3];
        }
    }

    #pragma unroll
    for (int m = 0; m < 16; ++m) {
        int r = m0 + m;
        if (r < rows) {
            size_t o = (size_t)(block0 + r) * H + j;
            q[o] = aq[m]; k[o] = ak[m]; v[o] = av[m];
        }
    }
}

// ---------------------------------------------------------------------------
// Kernel 2: per-edge score.  16 lanes per edge, float4 loads (each 16-lane
// group reads one contiguous 256B row of k and q).  4-step shuffle reduce
// within the group.  LDS 256-entry segment histogram, one global atomic per
// segment per block at the end (grid-stride persistent blocks).
// ---------------------------------------------------------------------------
__global__ __launch_bounds__(256) void edge_score(
    const float* __restrict__ q, const float* __restrict__ k,
    const int* __restrict__ ei, const int* __restrict__ batch,
    float* __restrict__ exps, float* __restrict__ denom,
    int E, int N)
{
    __shared__ float sden[NSEG];
    sden[threadIdx.x] = 0.f;
    __syncthreads();

    const int t      = threadIdx.x;
    const int lane16 = t & 15;
    const int grp    = t >> 4;            // 16 edge-groups per block
    const int step   = gridDim.x * 16;

    const float4* q4 = (const float4*)q;
    const float4* k4 = (const float4*)k;

    for (int e = blockIdx.x * 16 + grp; e < E; e += step) {
        int src = ei[e];
        int dst = ei[E + e];
        src = min(max(src, 0), N - 1);
        dst = min(max(dst, 0), N - 1);
        const float4 kv = k4[(size_t)src * 16 + lane16];
        const float4 qv = q4[(size_t)dst * 16 + lane16];
        float p = kv.x * qv.x + kv.y * qv.y + kv.z * qv.z + kv.w * qv.w;
        p += __shfl_xor(p, 1, 64);
        p += __shfl_xor(p, 2, 64);
        p += __shfl_xor(p, 4, 64);
        p += __shfl_xor(p, 8, 64);
        if (lane16 == 0) {
            float ex = __expf(p * 0.125f);
            exps[e] = ex;
            int seg = batch[src];
            seg = min(max(seg, 0), NSEG - 1);
            atomicAdd(&sden[seg], ex);
        }
    }
    __syncthreads();
    float d = sden[t];
    if (d != 0.f) atomicAdd(&denom[t], d);
}

// ---------------------------------------------------------------------------
// Kernel 3: normalize + scatter.  16 lanes per edge, float4 gather of v[src],
// 4 contiguous native fp32 atomics per lane into out[dest].
// ---------------------------------------------------------------------------
__global__ __launch_bounds__(256) void edge_scatter(
    const float* __restrict__ v, const float* __restrict__ exps,
    const float* __restrict__ denom,
    const int* __restrict__ ei, const int* __restrict__ batch,
    float* __restrict__ out, int E, int N)
{
    const int t      = threadIdx.x;
    const int lane16 = t & 15;
    const int grp    = t >> 4;
    const int step   = gridDim.x * 16;

    const float4* v4 = (const float4*)v;

    for (int e = blockIdx.x * 16 + grp; e < E; e += step) {
        int src = ei[e];
        int dst = ei[E + e];
        src = min(max(src, 0), N - 1);
        dst = min(max(dst, 0), N - 1);
        int seg = batch[src];
        seg = min(max(seg, 0), NSEG - 1);
        const float a = exps[e] / (denom[seg] + 1e-6f);
        const float4 vv = v4[(size_t)src * 16 + lane16];
        float* o = out + (size_t)dst * H + lane16 * 4;
        unsafeAtomicAdd(o + 0, vv.x * a);
        unsafeAtomicAdd(o + 1, vv.y * a);
        unsafeAtomicAdd(o + 2, vv.z * a);
        unsafeAtomicAdd(o + 3, vv.w * a);
    }
}

extern "C" void kernel_launch(void* const* d_in, const int* in_sizes, int n_in,
                              void* d_out, int out_size, void* d_ws, size_t ws_size,
                              hipStream_t stream)
{
    const float* x   = (const float*)d_in[0];
    const float* Wq  = (const float*)d_in[1];
    const float* bq  = (const float*)d_in[2];
    const float* Wk  = (const float*)d_in[3];
    const float* bk  = (const float*)d_in[4];
    const float* Wv  = (const float*)d_in[5];
    const float* bv  = (const float*)d_in[6];
    const int* ei    = (const int*)d_in[7];
    const int* batch = (const int*)d_in[8];

    const int N = in_sizes[8];        // 50000 nodes (batch has one entry per node)
    const int E = in_sizes[7] / 2;    // 800000 edges

    float* q     = (float*)d_ws;
    float* k     = q + (size_t)N * H;
    float* v     = k + (size_t)N * H;
    float* exps  = v + (size_t)N * H;
    float* denom = exps + E;          // 256 floats

    hipMemsetAsync(denom, 0, NSEG * sizeof(float), stream);
    hipMemsetAsync(d_out, 0, (size_t)out_size * sizeof(float), stream);

    qkv_proj<<<(N + BM - 1) / BM, 256, 0, stream>>>(
        x, Wq, bq, Wk, bk, Wv, bv, q, k, v, N);

    edge_score<<<2048, 256, 0, stream>>>(q, k, ei, batch, exps, denom, E, N);

    edge_scatter<<<2048, 256, 0, stream>>>(
        v, exps, denom, ei, batch, (float*)d_out, E, N);
}

// Round 3
// 725.361 us; speedup vs baseline: 1.3779x; 1.3779x over previous
//
#include <hip/hip_runtime.h>

#define H    64
#define F    256
#define BM   64
#define NSEG 256

// ---------------------------------------------------------------------------
// Kernel 1: fused QKV projection (unchanged from r1; ~40-60us, not the
// bottleneck).  Block = 256 threads, 64 node rows, x tile in LDS.
// ---------------------------------------------------------------------------
__global__ __launch_bounds__(256) void qkv_proj(
    const float* __restrict__ x,
    const float* __restrict__ Wq, const float* __restrict__ bq,
    const float* __restrict__ Wk, const float* __restrict__ bk,
    const float* __restrict__ Wv, const float* __restrict__ bv,
    float* __restrict__ q, float* __restrict__ k, float* __restrict__ v,
    int N)
{
    __shared__ float xs[BM][F];
    const int t = threadIdx.x;
    const int block0 = blockIdx.x * BM;
    const int rows = min(BM, N - block0);

    const float4* x4 = (const float4*)(x + (size_t)block0 * F);
    float4* xs4 = (float4*)&xs[0][0];
    #pragma unroll
    for (int it = 0; it < (BM * F / 4) / 256; ++it) {
        int idx = t + it * 256;
        int r = idx >> 6;
        float4 val = (r < rows) ? x4[idx] : make_float4(0.f, 0.f, 0.f, 0.f);
        xs4[idx] = val;
    }
    __syncthreads();

    const int j  = t & 63;
    const int m0 = (t >> 6) * 16;

    float aq[16], ak[16], av[16];
    const float bqj = bq[j], bkj = bk[j], bvj = bv[j];
    #pragma unroll
    for (int m = 0; m < 16; ++m) { aq[m] = bqj; ak[m] = bkj; av[m] = bvj; }

    for (int i = 0; i < F; i += 4) {
        float wq[4], wk[4], wv[4];
        #pragma unroll
        for (int u = 0; u < 4; ++u) {
            wq[u] = Wq[(i + u) * H + j];
            wk[u] = Wk[(i + u) * H + j];
            wv[u] = Wv[(i + u) * H + j];
        }
        #pragma unroll
        for (int m = 0; m < 16; ++m) {
            const float4 xv = *(const float4*)&xs[m0 + m][i];
            aq[m] += xv.x * wq[0] + xv.y * wq[1] + xv.z * wq[2] + xv.w * wq[3];
            ak[m] += xv.x * wk[0] + xv.y * wk[1] + xv.z * wk[2] + xv.w * wk[3];
            av[m] += xv.x * wv[0] + xv.y * wv[1] + xv.z * wv[2] + xv.w * wv[3];
        }
    }

    #pragma unroll
    for (int m = 0; m < 16; ++m) {
        int r = m0 + m;
        if (r < rows) {
            size_t o = (size_t)(block0 + r) * H + j;
            q[o] = aq[m]; k[o] = ak[m]; v[o] = av[m];
        }
    }
}

// ---------------------------------------------------------------------------
// Kernel 2: histogram of destination buckets (bucket = 16 dst nodes).
// ---------------------------------------------------------------------------
__global__ __launch_bounds__(256) void hist_kernel(
    const int* __restrict__ ei, int* __restrict__ counts, int E, int N)
{
    int e = blockIdx.x * 256 + threadIdx.x;
    if (e >= E) return;
    int dst = ei[E + e];
    dst = min(max(dst, 0), N - 1);
    atomicAdd(&counts[dst >> 4], 1);
}

// ---------------------------------------------------------------------------
// Kernel 3: exclusive scan over NB bucket counts (single block, 1024 thr).
// Writes offsets[] and a working copy cursor[].
// ---------------------------------------------------------------------------
__global__ __launch_bounds__(1024) void scan_kernel(
    const int* __restrict__ counts, int* __restrict__ offsets,
    int* __restrict__ cursor, int NB)
{
    __shared__ int tmp[1024];
    __shared__ int carry;
    const int t = threadIdx.x;
    if (t == 0) carry = 0;
    __syncthreads();

    for (int base = 0; base < NB; base += 1024) {
        int i = base + t;
        int val = (i < NB) ? counts[i] : 0;
        tmp[t] = val;
        __syncthreads();
        for (int off = 1; off < 1024; off <<= 1) {
            int add = (t >= off) ? tmp[t - off] : 0;
            __syncthreads();
            tmp[t] += add;
            __syncthreads();
        }
        int excl = tmp[t] - val + carry;
        if (i < NB) { offsets[i] = excl; cursor[i] = excl; }
        __syncthreads();
        if (t == 0) carry += tmp[1023];
        __syncthreads();
    }
}

// ---------------------------------------------------------------------------
// Kernel 4: reorder edges into dst-bucket order.  Packed record:
//   bits 0-15 src, 16-19 dst&15, 20-27 seg (batch[src]).
// ---------------------------------------------------------------------------
__global__ __launch_bounds__(256) void reorder_kernel(
    const int* __restrict__ ei, const int* __restrict__ batch,
    int* __restrict__ cursor, unsigned* __restrict__ epack, int E, int N)
{
    int e = blockIdx.x * 256 + threadIdx.x;
    if (e >= E) return;
    int src = ei[e];
    int dst = ei[E + e];
    src = min(max(src, 0), N - 1);
    dst = min(max(dst, 0), N - 1);
    int seg = batch[src];
    seg = min(max(seg, 0), NSEG - 1);
    int pos = atomicAdd(&cursor[dst >> 4], 1);
    epack[pos] = (unsigned)src | ((unsigned)(dst & 15) << 16) | ((unsigned)seg << 20);
}

// ---------------------------------------------------------------------------
// Kernel 5: per-edge score in sorted order.  Persistent blocks, one bucket
// at a time: q rows of the bucket (4KB) stay L1-resident; k gathers random.
// 16 lanes/edge, float4 loads, 4-step shuffle reduce.  Per-block LDS denom
// histogram accumulated across ALL buckets, flushed once at the end.
// ---------------------------------------------------------------------------
__global__ __launch_bounds__(256) void score_kernel(
    const float* __restrict__ q, const float* __restrict__ k,
    const unsigned* __restrict__ epack,
    const int* __restrict__ offsets, const int* __restrict__ counts,
    float* __restrict__ exps, float* __restrict__ denom, int NB)
{
    __shared__ float sden[NSEG];
    const int t = threadIdx.x;
    sden[t] = 0.f;
    __syncthreads();

    const int lane16 = t & 15;
    const int grp    = t >> 4;
    const float4* q4 = (const float4*)q;
    const float4* k4 = (const float4*)k;

    for (int b = blockIdx.x; b < NB; b += gridDim.x) {
        const int off = offsets[b];
        const int cnt = counts[b];
        const int base = b << 4;
        for (int i = grp; i < cnt; i += 16) {
            const int pos = off + i;
            const unsigned p = epack[pos];
            const int src    = p & 0xFFFF;
            const int dst    = base + ((p >> 16) & 15);
            const float4 kv = k4[(size_t)src * 16 + lane16];
            const float4 qv = q4[(size_t)dst * 16 + lane16];
            float d = kv.x * qv.x + kv.y * qv.y + kv.z * qv.z + kv.w * qv.w;
            d += __shfl_xor(d, 1, 64);
            d += __shfl_xor(d, 2, 64);
            d += __shfl_xor(d, 4, 64);
            d += __shfl_xor(d, 8, 64);
            if (lane16 == 0) {
                float ex = __expf(d * 0.125f);
                exps[pos] = ex;
                atomicAdd(&sden[(p >> 20) & 255], ex);
            }
        }
    }
    __syncthreads();
    float dsum = sden[t];
    if (dsum != 0.f) atomicAdd(&denom[t], dsum);
}

// ---------------------------------------------------------------------------
// Kernel 6: accumulate.  One block per bucket.  LDS accumulator 16 rows x
// 64 cols (row stride 65 to spread banks), LDS fp32 atomics (NO global fp32
// atomics).  Lane l of a 16-lane group handles feature words l, l+16, l+32,
// l+48 -> per-instruction bank spread ~2-way.  Final 4KB coalesced store.
// ---------------------------------------------------------------------------
__global__ __launch_bounds__(256) void accum_kernel(
    const float* __restrict__ v, const float* __restrict__ exps,
    const unsigned* __restrict__ epack,
    const int* __restrict__ offsets, const int* __restrict__ counts,
    const float* __restrict__ denom, float* __restrict__ out, int NB, int N)
{
    __shared__ float acc[16 * 65];
    __shared__ float sden[NSEG];
    const int t = threadIdx.x;
    sden[t] = denom[t];
    #pragma unroll
    for (int i = t; i < 16 * 65; i += 256) acc[i] = 0.f;
    __syncthreads();

    const int b = blockIdx.x;
    const int off = offsets[b];
    const int cnt = counts[b];
    const int lane16 = t & 15;
    const int grp    = t >> 4;

    for (int i = grp; i < cnt; i += 16) {
        const int pos = off + i;
        const unsigned p = epack[pos];
        const float ex = exps[pos];
        const int src    = p & 0xFFFF;
        const int dstlow = (p >> 16) & 15;
        const int seg    = (p >> 20) & 255;
        const float a = ex / (sden[seg] + 1e-6f);
        const float* vrow = v + (size_t)src * H;
        #pragma unroll
        for (int u = 0; u < 4; ++u) {
            atomicAdd(&acc[dstlow * 65 + u * 16 + lane16],
                      vrow[u * 16 + lane16] * a);
        }
    }
    __syncthreads();

    const int r  = t >> 4;
    const int c0 = (t & 15) * 4;
    const int node = (b << 4) + r;
    if (node < N) {
        float4 o;
        o.x = acc[r * 65 + c0 + 0];
        o.y = acc[r * 65 + c0 + 1];
        o.z = acc[r * 65 + c0 + 2];
        o.w = acc[r * 65 + c0 + 3];
        *(float4*)(out + (size_t)node * H + c0) = o;
    }
}

extern "C" void kernel_launch(void* const* d_in, const int* in_sizes, int n_in,
                              void* d_out, int out_size, void* d_ws, size_t ws_size,
                              hipStream_t stream)
{
    const float* x   = (const float*)d_in[0];
    const float* Wq  = (const float*)d_in[1];
    const float* bq  = (const float*)d_in[2];
    const float* Wk  = (const float*)d_in[3];
    const float* bk  = (const float*)d_in[4];
    const float* Wv  = (const float*)d_in[5];
    const float* bv  = (const float*)d_in[6];
    const int* ei    = (const int*)d_in[7];
    const int* batch = (const int*)d_in[8];

    const int N  = in_sizes[8];       // 50000
    const int E  = in_sizes[7] / 2;   // 800000
    const int NB = (N + 15) >> 4;     // 3125 buckets of 16 dst nodes

    float*    q       = (float*)d_ws;
    float*    k       = q + (size_t)N * H;
    float*    v       = k + (size_t)N * H;
    float*    exps    = v + (size_t)N * H;
    unsigned* epack   = (unsigned*)(exps + E);
    int*      counts  = (int*)(epack + E);
    int*      offsets = counts + NB;
    int*      cursor  = offsets + NB;
    float*    denom   = (float*)(cursor + NB);

    hipMemsetAsync(counts, 0, NB * sizeof(int), stream);
    hipMemsetAsync(denom, 0, NSEG * sizeof(float), stream);

    qkv_proj<<<(N + BM - 1) / BM, 256, 0, stream>>>(
        x, Wq, bq, Wk, bk, Wv, bv, q, k, v, N);

    hist_kernel<<<(E + 255) / 256, 256, 0, stream>>>(ei, counts, E, N);

    scan_kernel<<<1, 1024, 0, stream>>>(counts, offsets, cursor, NB);

    reorder_kernel<<<(E + 255) / 256, 256, 0, stream>>>(
        ei, batch, cursor, epack, E, N);

    score_kernel<<<1024, 256, 0, stream>>>(
        q, k, epack, offsets, counts, exps, denom, NB);

    accum_kernel<<<NB, 256, 0, stream>>>(
        v, exps, epack, offsets, counts, denom, (float*)d_out, NB, N);
}

// Round 4
// 514.071 us; speedup vs baseline: 1.9442x; 1.4110x over previous
//
#include <hip/hip_runtime.h>

#define H    64
#define F    256
#define BM   64
#define NSEG 256

// ---------------------------------------------------------------------------
// Kernel 1: fused QKV projection (unchanged; ~VALU-bound, ~31us floor).
// ---------------------------------------------------------------------------
__global__ __launch_bounds__(256) void qkv_proj(
    const float* __restrict__ x,
    const float* __restrict__ Wq, const float* __restrict__ bq,
    const float* __restrict__ Wk, const float* __restrict__ bk,
    const float* __restrict__ Wv, const float* __restrict__ bv,
    float* __restrict__ q, float* __restrict__ k, float* __restrict__ v,
    int N)
{
    __shared__ float xs[BM][F];
    const int t = threadIdx.x;
    const int block0 = blockIdx.x * BM;
    const int rows = min(BM, N - block0);

    const float4* x4 = (const float4*)(x + (size_t)block0 * F);
    float4* xs4 = (float4*)&xs[0][0];
    #pragma unroll
    for (int it = 0; it < (BM * F / 4) / 256; ++it) {
        int idx = t + it * 256;
        int r = idx >> 6;
        float4 val = (r < rows) ? x4[idx] : make_float4(0.f, 0.f, 0.f, 0.f);
        xs4[idx] = val;
    }
    __syncthreads();

    const int j  = t & 63;
    const int m0 = (t >> 6) * 16;

    float aq[16], ak[16], av[16];
    const float bqj = bq[j], bkj = bk[j], bvj = bv[j];
    #pragma unroll
    for (int m = 0; m < 16; ++m) { aq[m] = bqj; ak[m] = bkj; av[m] = bvj; }

    for (int i = 0; i < F; i += 4) {
        float wq[4], wk[4], wv[4];
        #pragma unroll
        for (int u = 0; u < 4; ++u) {
            wq[u] = Wq[(i + u) * H + j];
            wk[u] = Wk[(i + u) * H + j];
            wv[u] = Wv[(i + u) * H + j];
        }
        #pragma unroll
        for (int m = 0; m < 16; ++m) {
            const float4 xv = *(const float4*)&xs[m0 + m][i];
            aq[m] += xv.x * wq[0] + xv.y * wq[1] + xv.z * wq[2] + xv.w * wq[3];
            ak[m] += xv.x * wk[0] + xv.y * wk[1] + xv.z * wk[2] + xv.w * wk[3];
            av[m] += xv.x * wv[0] + xv.y * wv[1] + xv.z * wv[2] + xv.w * wv[3];
        }
    }

    #pragma unroll
    for (int m = 0; m < 16; ++m) {
        int r = m0 + m;
        if (r < rows) {
            size_t o = (size_t)(block0 + r) * H + j;
            q[o] = aq[m]; k[o] = ak[m]; v[o] = av[m];
        }
    }
}

// ---------------------------------------------------------------------------
// Kernel 2: per-node in-degree histogram.
// ---------------------------------------------------------------------------
__global__ __launch_bounds__(256) void hist_kernel(
    const int* __restrict__ ei, int* __restrict__ counts, int E, int N)
{
    int e = blockIdx.x * 256 + threadIdx.x;
    if (e >= E) return;
    int dst = ei[E + e];
    dst = min(max(dst, 0), N - 1);
    atomicAdd(&counts[dst], 1);
}

// ---------------------------------------------------------------------------
// Kernel 3: exclusive scan over N per-node counts, region sizes padded to
// multiples of 4 so every node's epack/exps slice is 16B-aligned.
// Single block, 1024 threads, chunked two-phase scan.
// ---------------------------------------------------------------------------
__global__ __launch_bounds__(1024) void scan_kernel(
    const int* __restrict__ counts, int* __restrict__ offsets,
    int* __restrict__ cursor, int n)
{
    __shared__ int part[1024];
    const int t = threadIdx.x;
    const int C = (n + 1023) >> 10;
    const int b0 = t * C, b1 = min(b0 + C, n);

    int s = 0;
    for (int i = b0; i < b1; ++i) s += (counts[i] + 3) & ~3;
    part[t] = s;
    __syncthreads();
    for (int off = 1; off < 1024; off <<= 1) {
        int a = (t >= off) ? part[t - off] : 0;
        __syncthreads();
        part[t] += a;
        __syncthreads();
    }
    int run = part[t] - s;
    for (int i = b0; i < b1; ++i) {
        int rc = (counts[i] + 3) & ~3;
        offsets[i] = run; cursor[i] = run;
        run += rc;
    }
}

// ---------------------------------------------------------------------------
// Kernel 4: reorder edges into dst-node order.  pack = src(16b) | seg(8b)<<16.
// ---------------------------------------------------------------------------
__global__ __launch_bounds__(256) void reorder_kernel(
    const int* __restrict__ ei, const int* __restrict__ batch,
    int* __restrict__ cursor, unsigned* __restrict__ epack, int E, int N)
{
    int e = blockIdx.x * 256 + threadIdx.x;
    if (e >= E) return;
    int src = ei[e];
    int dst = ei[E + e];
    src = min(max(src, 0), N - 1);
    dst = min(max(dst, 0), N - 1);
    int seg = batch[src];
    seg = min(max(seg, 0), NSEG - 1);
    int pos = atomicAdd(&cursor[dst], 1);
    epack[pos] = (unsigned)src | ((unsigned)seg << 16);
}

// ---------------------------------------------------------------------------
// Kernel 5: score.  Persistent grid, one wave per dst node (grid-stride):
// q[dst] loaded ONCE per node into registers.  4 edges in flight per wave
// (16-lane groups, float4 k gathers, 4-step shuffle reduce).  Per-block LDS
// denom histogram flushed once (1024 blocks -> 262K global atomics).
// ---------------------------------------------------------------------------
__global__ __launch_bounds__(256) void score_kernel(
    const float* __restrict__ q, const float* __restrict__ k,
    const unsigned* __restrict__ epack,
    const int* __restrict__ offsets, const int* __restrict__ counts,
    float* __restrict__ exps, float* __restrict__ denom, int N)
{
    __shared__ float sden[NSEG];
    const int t = threadIdx.x;
    sden[t] = 0.f;
    __syncthreads();

    const int lane16 = t & 15;
    const int grp    = (t >> 4) & 3;     // 16-lane group within the wave
    const int wave   = t >> 6;
    const int nwaves = gridDim.x * 4;

    const float4* q4 = (const float4*)q;
    const float4* k4 = (const float4*)k;

    for (int n = blockIdx.x * 4 + wave; n < N; n += nwaves) {
        const int off = offsets[n];
        const int cnt = counts[n];
        if (cnt == 0) continue;
        const float4 qv = q4[(size_t)n * 16 + lane16];
        for (int i = grp; i < cnt; i += 4) {
            const int pos = off + i;
            const unsigned p = epack[pos];
            const int src = p & 0xFFFF;
            const float4 kv = k4[(size_t)src * 16 + lane16];
            float d = kv.x * qv.x + kv.y * qv.y + kv.z * qv.z + kv.w * qv.w;
            d += __shfl_xor(d, 1, 64);
            d += __shfl_xor(d, 2, 64);
            d += __shfl_xor(d, 4, 64);
            d += __shfl_xor(d, 8, 64);
            if (lane16 == 0) {
                float ex = __expf(d * 0.125f);
                exps[pos] = ex;
                atomicAdd(&sden[(p >> 16) & 255], ex);
            }
        }
    }
    __syncthreads();
    float ds = sden[t];
    if (ds != 0.f) atomicAdd(&denom[t], ds);
}

// ---------------------------------------------------------------------------
// Kernel 6: accumulate.  One wave per dst node, lane = feature.  Register
// accumulator, ZERO atomics.  Edge metadata read as wave-uniform uint4 /
// float4 broadcast loads (offsets are 4-aligned); v rows gathered coalesced
// (256B/wave); one coalesced store per node.
// ---------------------------------------------------------------------------
__global__ __launch_bounds__(256) void accum_kernel(
    const float* __restrict__ v, const float* __restrict__ exps,
    const unsigned* __restrict__ epack,
    const int* __restrict__ offsets, const int* __restrict__ counts,
    const float* __restrict__ denom, float* __restrict__ out, int N)
{
    __shared__ float sden[NSEG];
    const int t = threadIdx.x;
    sden[t] = denom[t];
    __syncthreads();

    const int lane = t & 63;
    const int wave = t >> 6;
    const int n = blockIdx.x * 4 + wave;
    if (n >= N) return;

    const int off = offsets[n];
    const int cnt = counts[n];

    float acc = 0.f;
    int i = 0;
    for (; i + 4 <= cnt; i += 4) {
        const uint4  pp = *(const uint4*)(epack + off + i);
        const float4 ee = *(const float4*)(exps + off + i);
        const float a0 = ee.x / (sden[(pp.x >> 16) & 255] + 1e-6f);
        const float a1 = ee.y / (sden[(pp.y >> 16) & 255] + 1e-6f);
        const float a2 = ee.z / (sden[(pp.z >> 16) & 255] + 1e-6f);
        const float a3 = ee.w / (sden[(pp.w >> 16) & 255] + 1e-6f);
        const float v0 = v[(size_t)(pp.x & 0xFFFF) * H + lane];
        const float v1 = v[(size_t)(pp.y & 0xFFFF) * H + lane];
        const float v2 = v[(size_t)(pp.z & 0xFFFF) * H + lane];
        const float v3 = v[(size_t)(pp.w & 0xFFFF) * H + lane];
        acc += v0 * a0;
        acc += v1 * a1;
        acc += v2 * a2;
        acc += v3 * a3;
    }
    for (; i < cnt; ++i) {
        const unsigned p = epack[off + i];
        const float a = exps[off + i] / (sden[(p >> 16) & 255] + 1e-6f);
        acc += v[(size_t)(p & 0xFFFF) * H + lane] * a;
    }
    out[(size_t)n * H + lane] = acc;
}

extern "C" void kernel_launch(void* const* d_in, const int* in_sizes, int n_in,
                              void* d_out, int out_size, void* d_ws, size_t ws_size,
                              hipStream_t stream)
{
    const float* x   = (const float*)d_in[0];
    const float* Wq  = (const float*)d_in[1];
    const float* bq  = (const float*)d_in[2];
    const float* Wk  = (const float*)d_in[3];
    const float* bk  = (const float*)d_in[4];
    const float* Wv  = (const float*)d_in[5];
    const float* bv  = (const float*)d_in[6];
    const int* ei    = (const int*)d_in[7];
    const int* batch = (const int*)d_in[8];

    const int N = in_sizes[8];        // 50000
    const int E = in_sizes[7] / 2;    // 800000
    const int EP = E + 3 * N + 16;    // padded edge-slot capacity (4-aligned regions)

    float*    q       = (float*)d_ws;
    float*    k       = q + (size_t)N * H;
    float*    v       = k + (size_t)N * H;
    float*    exps    = v + (size_t)N * H;
    unsigned* epack   = (unsigned*)(exps + EP);
    int*      counts  = (int*)(epack + EP);
    int*      offsets = counts + N;
    int*      cursor  = offsets + N;
    float*    denom   = (float*)(cursor + N);

    hipMemsetAsync(counts, 0, N * sizeof(int), stream);
    hipMemsetAsync(denom, 0, NSEG * sizeof(float), stream);

    qkv_proj<<<(N + BM - 1) / BM, 256, 0, stream>>>(
        x, Wq, bq, Wk, bk, Wv, bv, q, k, v, N);

    hist_kernel<<<(E + 255) / 256, 256, 0, stream>>>(ei, counts, E, N);

    scan_kernel<<<1, 1024, 0, stream>>>(counts, offsets, cursor, N);

    reorder_kernel<<<(E + 255) / 256, 256, 0, stream>>>(
        ei, batch, cursor, epack, E, N);

    score_kernel<<<1024, 256, 0, stream>>>(
        q, k, epack, offsets, counts, exps, denom, N);

    accum_kernel<<<(N + 3) / 4, 256, 0, stream>>>(
        v, exps, epack, offsets, counts, denom, (float*)d_out, N);
}

// Round 5
// 489.307 us; speedup vs baseline: 2.0426x; 1.0506x over previous
//
#include <hip/hip_runtime.h>

#define H    64
#define F    256
#define BM   32
#define NSEG 256

// ---------------------------------------------------------------------------
// Kernel 1: fused QKV projection + in-degree histogram.
// BM=32 rows/block, 256 threads, 32KB LDS tile -> 5 blocks/CU (20 waves,
// ~62% occupancy cap) vs the old 64KB/2-block version (25% cap).
// Thread (j = t&63, group g = t>>6) computes 8 nodes x {q,k,v} = 24 accs.
// Each block also issues one 512-edge chunk of the dst-histogram (independent
// work, fire-and-forget atomics) so the old hist_kernel dispatch disappears.
// ---------------------------------------------------------------------------
__global__ __launch_bounds__(256) void qkv_hist(
    const float* __restrict__ x,
    const float* __restrict__ Wq, const float* __restrict__ bq,
    const float* __restrict__ Wk, const float* __restrict__ bk,
    const float* __restrict__ Wv, const float* __restrict__ bv,
    float* __restrict__ q, float* __restrict__ k, float* __restrict__ v,
    const int* __restrict__ ei, int* __restrict__ counts,
    int N, int E)
{
    __shared__ float xs[BM][F];
    const int t = threadIdx.x;

    // --- fused histogram chunk (independent; atomics need no result) ---
    {
        int e = blockIdx.x * 512 + t;
        #pragma unroll
        for (int u = 0; u < 2; ++u) {
            if (e < E) {
                int dst = ei[E + e];
                dst = min(max(dst, 0), N - 1);
                atomicAdd(&counts[dst], 1);
            }
            e += 256;
        }
    }

    const int block0 = blockIdx.x * BM;
    const int rows = min(BM, N - block0);

    const float4* x4 = (const float4*)(x + (size_t)block0 * F);
    float4* xs4 = (float4*)&xs[0][0];
    #pragma unroll
    for (int it = 0; it < (BM * F / 4) / 256; ++it) {
        int idx = t + it * 256;
        int r = idx >> 6;                        // F/4 = 64 float4 per row
        float4 val = (r < rows) ? x4[idx] : make_float4(0.f, 0.f, 0.f, 0.f);
        xs4[idx] = val;
    }
    __syncthreads();

    const int j  = t & 63;
    const int m0 = (t >> 6) * 8;

    float aq[8], ak[8], av[8];
    const float bqj = bq[j], bkj = bk[j], bvj = bv[j];
    #pragma unroll
    for (int m = 0; m < 8; ++m) { aq[m] = bqj; ak[m] = bkj; av[m] = bvj; }

    for (int i = 0; i < F; i += 4) {
        float wq[4], wk[4], wv[4];
        #pragma unroll
        for (int u = 0; u < 4; ++u) {
            wq[u] = Wq[(i + u) * H + j];
            wk[u] = Wk[(i + u) * H + j];
            wv[u] = Wv[(i + u) * H + j];
        }
        #pragma unroll
        for (int m = 0; m < 8; ++m) {
            const float4 xv = *(const float4*)&xs[m0 + m][i];
            aq[m] += xv.x * wq[0] + xv.y * wq[1] + xv.z * wq[2] + xv.w * wq[3];
            ak[m] += xv.x * wk[0] + xv.y * wk[1] + xv.z * wk[2] + xv.w * wk[3];
            av[m] += xv.x * wv[0] + xv.y * wv[1] + xv.z * wv[2] + xv.w * wv[3];
        }
    }

    #pragma unroll
    for (int m = 0; m < 8; ++m) {
        int r = m0 + m;
        if (r < rows) {
            size_t o = (size_t)(block0 + r) * H + j;
            q[o] = aq[m]; k[o] = ak[m]; v[o] = av[m];
        }
    }
}

// ---------------------------------------------------------------------------
// Kernel 2: exclusive scan over N per-node counts, region sizes padded to
// multiples of 4 so every node's epack/exps slice is 16B-aligned.
// ---------------------------------------------------------------------------
__global__ __launch_bounds__(1024) void scan_kernel(
    const int* __restrict__ counts, int* __restrict__ offsets,
    int* __restrict__ cursor, int n)
{
    __shared__ int part[1024];
    const int t = threadIdx.x;
    const int C = (n + 1023) >> 10;
    const int b0 = t * C, b1 = min(b0 + C, n);

    int s = 0;
    for (int i = b0; i < b1; ++i) s += (counts[i] + 3) & ~3;
    part[t] = s;
    __syncthreads();
    for (int off = 1; off < 1024; off <<= 1) {
        int a = (t >= off) ? part[t - off] : 0;
        __syncthreads();
        part[t] += a;
        __syncthreads();
    }
    int run = part[t] - s;
    for (int i = b0; i < b1; ++i) {
        int rc = (counts[i] + 3) & ~3;
        offsets[i] = run; cursor[i] = run;
        run += rc;
    }
}

// ---------------------------------------------------------------------------
// Kernel 3: reorder edges into dst-node order.  pack = src(16b) | seg(8b)<<16.
// ---------------------------------------------------------------------------
__global__ __launch_bounds__(256) void reorder_kernel(
    const int* __restrict__ ei, const int* __restrict__ batch,
    int* __restrict__ cursor, unsigned* __restrict__ epack, int E, int N)
{
    int e = blockIdx.x * 256 + threadIdx.x;
    if (e >= E) return;
    int src = ei[e];
    int dst = ei[E + e];
    src = min(max(src, 0), N - 1);
    dst = min(max(dst, 0), N - 1);
    int seg = batch[src];
    seg = min(max(seg, 0), NSEG - 1);
    int pos = atomicAdd(&cursor[dst], 1);
    epack[pos] = (unsigned)src | ((unsigned)seg << 16);
}

// ---------------------------------------------------------------------------
// Kernel 4: score.  Persistent grid, one wave per dst node (grid-stride):
// q[dst] loaded ONCE per node into registers.  4 edges in flight per wave
// (16-lane groups, float4 k gathers, 4-step shuffle reduce).  Per-block LDS
// denom histogram flushed once.
// ---------------------------------------------------------------------------
__global__ __launch_bounds__(256) void score_kernel(
    const float* __restrict__ q, const float* __restrict__ k,
    const unsigned* __restrict__ epack,
    const int* __restrict__ offsets, const int* __restrict__ counts,
    float* __restrict__ exps, float* __restrict__ denom, int N)
{
    __shared__ float sden[NSEG];
    const int t = threadIdx.x;
    sden[t] = 0.f;
    __syncthreads();

    const int lane16 = t & 15;
    const int grp    = (t >> 4) & 3;
    const int wave   = t >> 6;
    const int nwaves = gridDim.x * 4;

    const float4* q4 = (const float4*)q;
    const float4* k4 = (const float4*)k;

    for (int n = blockIdx.x * 4 + wave; n < N; n += nwaves) {
        const int off = offsets[n];
        const int cnt = counts[n];
        if (cnt == 0) continue;
        const float4 qv = q4[(size_t)n * 16 + lane16];
        for (int i = grp; i < cnt; i += 4) {
            const int pos = off + i;
            const unsigned p = epack[pos];
            const int src = p & 0xFFFF;
            const float4 kv = k4[(size_t)src * 16 + lane16];
            float d = kv.x * qv.x + kv.y * qv.y + kv.z * qv.z + kv.w * qv.w;
            d += __shfl_xor(d, 1, 64);
            d += __shfl_xor(d, 2, 64);
            d += __shfl_xor(d, 4, 64);
            d += __shfl_xor(d, 8, 64);
            if (lane16 == 0) {
                float ex = __expf(d * 0.125f);
                exps[pos] = ex;
                atomicAdd(&sden[(p >> 16) & 255], ex);
            }
        }
    }
    __syncthreads();
    float ds = sden[t];
    if (ds != 0.f) atomicAdd(&denom[t], ds);
}

// ---------------------------------------------------------------------------
// Kernel 5: accumulate.  One wave per dst node, lane = feature.  Register
// accumulator, ZERO atomics.  Wave-uniform uint4/float4 metadata broadcast
// loads (offsets 4-aligned); coalesced v-row gathers; one store per node.
// ---------------------------------------------------------------------------
__global__ __launch_bounds__(256) void accum_kernel(
    const float* __restrict__ v, const float* __restrict__ exps,
    const unsigned* __restrict__ epack,
    const int* __restrict__ offsets, const int* __restrict__ counts,
    const float* __restrict__ denom, float* __restrict__ out, int N)
{
    __shared__ float sden[NSEG];
    const int t = threadIdx.x;
    sden[t] = denom[t];
    __syncthreads();

    const int lane = t & 63;
    const int wave = t >> 6;
    const int n = blockIdx.x * 4 + wave;
    if (n >= N) return;

    const int off = offsets[n];
    const int cnt = counts[n];

    float acc = 0.f;
    int i = 0;
    for (; i + 4 <= cnt; i += 4) {
        const uint4  pp = *(const uint4*)(epack + off + i);
        const float4 ee = *(const float4*)(exps + off + i);
        const float a0 = ee.x / (sden[(pp.x >> 16) & 255] + 1e-6f);
        const float a1 = ee.y / (sden[(pp.y >> 16) & 255] + 1e-6f);
        const float a2 = ee.z / (sden[(pp.z >> 16) & 255] + 1e-6f);
        const float a3 = ee.w / (sden[(pp.w >> 16) & 255] + 1e-6f);
        const float v0 = v[(size_t)(pp.x & 0xFFFF) * H + lane];
        const float v1 = v[(size_t)(pp.y & 0xFFFF) * H + lane];
        const float v2 = v[(size_t)(pp.z & 0xFFFF) * H + lane];
        const float v3 = v[(size_t)(pp.w & 0xFFFF) * H + lane];
        acc += v0 * a0;
        acc += v1 * a1;
        acc += v2 * a2;
        acc += v3 * a3;
    }
    for (; i < cnt; ++i) {
        const unsigned p = epack[off + i];
        const float a = exps[off + i] / (sden[(p >> 16) & 255] + 1e-6f);
        acc += v[(size_t)(p & 0xFFFF) * H + lane] * a;
    }
    out[(size_t)n * H + lane] = acc;
}

extern "C" void kernel_launch(void* const* d_in, const int* in_sizes, int n_in,
                              void* d_out, int out_size, void* d_ws, size_t ws_size,
                              hipStream_t stream)
{
    const float* x   = (const float*)d_in[0];
    const float* Wq  = (const float*)d_in[1];
    const float* bq  = (const float*)d_in[2];
    const float* Wk  = (const float*)d_in[3];
    const float* bk  = (const float*)d_in[4];
    const float* Wv  = (const float*)d_in[5];
    const float* bv  = (const float*)d_in[6];
    const int* ei    = (const int*)d_in[7];
    const int* batch = (const int*)d_in[8];

    const int N = in_sizes[8];        // 50000
    const int E = in_sizes[7] / 2;    // 800000
    const int EP = E + 3 * N + 16;    // padded edge-slot capacity

    float*    q       = (float*)d_ws;
    float*    k       = q + (size_t)N * H;
    float*    v       = k + (size_t)N * H;
    float*    exps    = v + (size_t)N * H;
    unsigned* epack   = (unsigned*)(exps + EP);
    int*      counts  = (int*)(epack + EP);
    int*      offsets = counts + N;
    int*      cursor  = offsets + N;
    float*    denom   = (float*)(cursor + N);

    hipMemsetAsync(counts, 0, N * sizeof(int), stream);
    hipMemsetAsync(denom, 0, NSEG * sizeof(float), stream);

    const int QB = (N + BM - 1) / BM;   // 1563 blocks (also covers E/512 hist chunks)

    qkv_hist<<<QB, 256, 0, stream>>>(
        x, Wq, bq, Wk, bk, Wv, bv, q, k, v, ei, counts, N, E);

    scan_kernel<<<1, 1024, 0, stream>>>(counts, offsets, cursor, N);

    reorder_kernel<<<(E + 255) / 256, 256, 0, stream>>>(
        ei, batch, cursor, epack, E, N);

    score_kernel<<<1024, 256, 0, stream>>>(
        q, k, epack, offsets, counts, exps, denom, N);

    accum_kernel<<<(N + 3) / 4, 256, 0, stream>>>(
        v, exps, epack, offsets, counts, denom, (float*)d_out, N);
}

// Round 6
// 372.113 us; speedup vs baseline: 2.6859x; 1.3149x over previous
//
#include <hip/hip_runtime.h>

#define H    64
#define F    256
#define BM   32
#define NSEG 256
#define SCB  2048   // scan elements per block

// ---------------------------------------------------------------------------
// Kernel 1: fused QKV projection + in-degree histogram.
// BM=32 rows/block, 256 threads, 32KB LDS tile.  Thread (j=t&63, g=t>>6)
// computes 8 nodes x {q,k,v} = 24 accumulators as pure fmaf chains
// (exactly 4 v_fmac per 4 MACs -- the r5 '+' chain emitted mul+3fma+add).
// ---------------------------------------------------------------------------
__global__ __launch_bounds__(256) void qkv_hist(
    const float* __restrict__ x,
    const float* __restrict__ Wq, const float* __restrict__ bq,
    const float* __restrict__ Wk, const float* __restrict__ bk,
    const float* __restrict__ Wv, const float* __restrict__ bv,
    float* __restrict__ q, float* __restrict__ k, float* __restrict__ v,
    const int* __restrict__ ei, int* __restrict__ counts,
    int N, int E)
{
    __shared__ float xs[BM][F];
    const int t = threadIdx.x;

    // --- fused histogram chunk (independent; atomics need no result) ---
    {
        int e = blockIdx.x * 512 + t;
        #pragma unroll
        for (int u = 0; u < 2; ++u) {
            if (e < E) {
                int dst = ei[E + e];
                dst = min(max(dst, 0), N - 1);
                atomicAdd(&counts[dst], 1);
            }
            e += 256;
        }
    }

    const int block0 = blockIdx.x * BM;
    const int rows = min(BM, N - block0);

    const float4* x4 = (const float4*)(x + (size_t)block0 * F);
    float4* xs4 = (float4*)&xs[0][0];
    #pragma unroll
    for (int it = 0; it < (BM * F / 4) / 256; ++it) {
        int idx = t + it * 256;
        int r = idx >> 6;                        // F/4 = 64 float4 per row
        float4 val = (r < rows) ? x4[idx] : make_float4(0.f, 0.f, 0.f, 0.f);
        xs4[idx] = val;
    }
    __syncthreads();

    const int j  = t & 63;
    const int m0 = (t >> 6) * 8;

    float aq[8], ak[8], av[8];
    const float bqj = bq[j], bkj = bk[j], bvj = bv[j];
    #pragma unroll
    for (int m = 0; m < 8; ++m) { aq[m] = bqj; ak[m] = bkj; av[m] = bvj; }

    for (int i = 0; i < F; i += 4) {
        float wq[4], wk[4], wv[4];
        #pragma unroll
        for (int u = 0; u < 4; ++u) {
            wq[u] = Wq[(i + u) * H + j];
            wk[u] = Wk[(i + u) * H + j];
            wv[u] = Wv[(i + u) * H + j];
        }
        #pragma unroll
        for (int m = 0; m < 8; ++m) {
            const float4 xv = *(const float4*)&xs[m0 + m][i];
            aq[m] = fmaf(xv.x, wq[0], aq[m]);
            aq[m] = fmaf(xv.y, wq[1], aq[m]);
            aq[m] = fmaf(xv.z, wq[2], aq[m]);
            aq[m] = fmaf(xv.w, wq[3], aq[m]);
            ak[m] = fmaf(xv.x, wk[0], ak[m]);
            ak[m] = fmaf(xv.y, wk[1], ak[m]);
            ak[m] = fmaf(xv.z, wk[2], ak[m]);
            ak[m] = fmaf(xv.w, wk[3], ak[m]);
            av[m] = fmaf(xv.x, wv[0], av[m]);
            av[m] = fmaf(xv.y, wv[1], av[m]);
            av[m] = fmaf(xv.z, wv[2], av[m]);
            av[m] = fmaf(xv.w, wv[3], av[m]);
        }
    }

    #pragma unroll
    for (int m = 0; m < 8; ++m) {
        int r = m0 + m;
        if (r < rows) {
            size_t o = (size_t)(block0 + r) * H + j;
            q[o] = aq[m]; k[o] = ak[m]; v[o] = av[m];
        }
    }
}

// ---------------------------------------------------------------------------
// Scan phase A: per-block local exclusive scan of padded counts (8/thread),
// writes local offsets + per-block sum.
// ---------------------------------------------------------------------------
__global__ __launch_bounds__(256) void scanA(
    const int* __restrict__ counts, int* __restrict__ offsets,
    int* __restrict__ bsum, int n)
{
    __shared__ int ps[256];
    const int t = threadIdx.x;
    const int i0 = blockIdx.x * SCB + t * 8;
    int loc[8];
    int s = 0;
    #pragma unroll
    for (int u = 0; u < 8; ++u) {
        int i = i0 + u;
        int c = (i < n) ? ((counts[i] + 3) & ~3) : 0;
        loc[u] = s; s += c;
    }
    ps[t] = s;
    __syncthreads();
    for (int off = 1; off < 256; off <<= 1) {
        int a = (t >= off) ? ps[t - off] : 0;
        __syncthreads();
        ps[t] += a;
        __syncthreads();
    }
    const int base = ps[t] - s;
    #pragma unroll
    for (int u = 0; u < 8; ++u) {
        int i = i0 + u;
        if (i < n) offsets[i] = base + loc[u];
    }
    if (t == 255) bsum[blockIdx.x] = ps[255];
}

// Scan phase B: exclusive scan of the ~25 block sums (serial, tiny).
__global__ void scanB(int* __restrict__ bsum, int nb)
{
    if (threadIdx.x == 0 && blockIdx.x == 0) {
        int run = 0;
        for (int i = 0; i < nb; ++i) { int v = bsum[i]; bsum[i] = run; run += v; }
    }
}

// Scan phase C: add block base, emit offsets + cursor.
__global__ __launch_bounds__(256) void scanC(
    const int* __restrict__ bsum, int* __restrict__ offsets,
    int* __restrict__ cursor, int n)
{
    const int i0 = blockIdx.x * SCB + threadIdx.x * 8;
    const int add = bsum[blockIdx.x];
    #pragma unroll
    for (int u = 0; u < 8; ++u) {
        int i = i0 + u;
        if (i < n) { int o = offsets[i] + add; offsets[i] = o; cursor[i] = o; }
    }
}

// ---------------------------------------------------------------------------
// Reorder edges into dst-node order.  pack = src(16b) | seg(8b)<<16.
// ---------------------------------------------------------------------------
__global__ __launch_bounds__(256) void reorder_kernel(
    const int* __restrict__ ei, const int* __restrict__ batch,
    int* __restrict__ cursor, unsigned* __restrict__ epack, int E, int N)
{
    int e = blockIdx.x * 256 + threadIdx.x;
    if (e >= E) return;
    int src = ei[e];
    int dst = ei[E + e];
    src = min(max(src, 0), N - 1);
    dst = min(max(dst, 0), N - 1);
    int seg = batch[src];
    seg = min(max(seg, 0), NSEG - 1);
    int pos = atomicAdd(&cursor[dst], 1);
    epack[pos] = (unsigned)src | ((unsigned)seg << 16);
}

// ---------------------------------------------------------------------------
// Score: persistent grid, one wave per dst node; q[dst] in registers across
// its edges; 4 edges in flight (16-lane groups, float4 k gathers, 4-step
// shuffle reduce).  Per-block LDS denom histogram flushed once.
// ---------------------------------------------------------------------------
__global__ __launch_bounds__(256) void score_kernel(
    const float* __restrict__ q, const float* __restrict__ k,
    const unsigned* __restrict__ epack,
    const int* __restrict__ offsets, const int* __restrict__ counts,
    float* __restrict__ exps, float* __restrict__ denom, int N)
{
    __shared__ float sden[NSEG];
    const int t = threadIdx.x;
    sden[t] = 0.f;
    __syncthreads();

    const int lane16 = t & 15;
    const int grp    = (t >> 4) & 3;
    const int wave   = t >> 6;
    const int nwaves = gridDim.x * 4;

    const float4* q4 = (const float4*)q;
    const float4* k4 = (const float4*)k;

    for (int n = blockIdx.x * 4 + wave; n < N; n += nwaves) {
        const int off = offsets[n];
        const int cnt = counts[n];
        if (cnt == 0) continue;
        const float4 qv = q4[(size_t)n * 16 + lane16];
        for (int i = grp; i < cnt; i += 4) {
            const int pos = off + i;
            const unsigned p = epack[pos];
            const int src = p & 0xFFFF;
            const float4 kv = k4[(size_t)src * 16 + lane16];
            float d = kv.x * qv.x + kv.y * qv.y + kv.z * qv.z + kv.w * qv.w;
            d += __shfl_xor(d, 1, 64);
            d += __shfl_xor(d, 2, 64);
            d += __shfl_xor(d, 4, 64);
            d += __shfl_xor(d, 8, 64);
            if (lane16 == 0) {
                float ex = __expf(d * 0.125f);
                exps[pos] = ex;
                atomicAdd(&sden[(p >> 16) & 255], ex);
            }
        }
    }
    __syncthreads();
    float ds = sden[t];
    if (ds != 0.f) atomicAdd(&denom[t], ds);
}

// ---------------------------------------------------------------------------
// Accumulate: one wave per dst node, lane = feature, register accumulator,
// zero atomics.  LDS reciprocal table (256 divides total instead of 800K
// per-edge divides).  8-wide unrolled edge loop for load ILP.
// ---------------------------------------------------------------------------
__global__ __launch_bounds__(256) void accum_kernel(
    const float* __restrict__ v, const float* __restrict__ exps,
    const unsigned* __restrict__ epack,
    const int* __restrict__ offsets, const int* __restrict__ counts,
    const float* __restrict__ denom, float* __restrict__ out, int N)
{
    __shared__ float rden[NSEG];
    const int t = threadIdx.x;
    rden[t] = 1.0f / (denom[t] + 1e-6f);
    __syncthreads();

    const int lane = t & 63;
    const int wave = t >> 6;
    const int n = blockIdx.x * 4 + wave;
    if (n >= N) return;

    const int off = offsets[n];
    const int cnt = counts[n];

    float acc = 0.f;
    int i = 0;
    for (; i + 8 <= cnt; i += 8) {
        const uint4  pa = *(const uint4*)(epack + off + i);
        const uint4  pb = *(const uint4*)(epack + off + i + 4);
        const float4 ea = *(const float4*)(exps + off + i);
        const float4 eb = *(const float4*)(exps + off + i + 4);
        const float v0 = v[(size_t)(pa.x & 0xFFFF) * H + lane];
        const float v1 = v[(size_t)(pa.y & 0xFFFF) * H + lane];
        const float v2 = v[(size_t)(pa.z & 0xFFFF) * H + lane];
        const float v3 = v[(size_t)(pa.w & 0xFFFF) * H + lane];
        const float v4_ = v[(size_t)(pb.x & 0xFFFF) * H + lane];
        const float v5 = v[(size_t)(pb.y & 0xFFFF) * H + lane];
        const float v6 = v[(size_t)(pb.z & 0xFFFF) * H + lane];
        const float v7 = v[(size_t)(pb.w & 0xFFFF) * H + lane];
        acc = fmaf(v0, ea.x * rden[(pa.x >> 16) & 255], acc);
        acc = fmaf(v1, ea.y * rden[(pa.y >> 16) & 255], acc);
        acc = fmaf(v2, ea.z * rden[(pa.z >> 16) & 255], acc);
        acc = fmaf(v3, ea.w * rden[(pa.w >> 16) & 255], acc);
        acc = fmaf(v4_, eb.x * rden[(pb.x >> 16) & 255], acc);
        acc = fmaf(v5, eb.y * rden[(pb.y >> 16) & 255], acc);
        acc = fmaf(v6, eb.z * rden[(pb.z >> 16) & 255], acc);
        acc = fmaf(v7, eb.w * rden[(pb.w >> 16) & 255], acc);
    }
    for (; i + 4 <= cnt; i += 4) {
        const uint4  pp = *(const uint4*)(epack + off + i);
        const float4 ee = *(const float4*)(exps + off + i);
        const float v0 = v[(size_t)(pp.x & 0xFFFF) * H + lane];
        const float v1 = v[(size_t)(pp.y & 0xFFFF) * H + lane];
        const float v2 = v[(size_t)(pp.z & 0xFFFF) * H + lane];
        const float v3 = v[(size_t)(pp.w & 0xFFFF) * H + lane];
        acc = fmaf(v0, ee.x * rden[(pp.x >> 16) & 255], acc);
        acc = fmaf(v1, ee.y * rden[(pp.y >> 16) & 255], acc);
        acc = fmaf(v2, ee.z * rden[(pp.z >> 16) & 255], acc);
        acc = fmaf(v3, ee.w * rden[(pp.w >> 16) & 255], acc);
    }
    for (; i < cnt; ++i) {
        const unsigned p = epack[off + i];
        acc = fmaf(v[(size_t)(p & 0xFFFF) * H + lane],
                   exps[off + i] * rden[(p >> 16) & 255], acc);
    }
    out[(size_t)n * H + lane] = acc;
}

extern "C" void kernel_launch(void* const* d_in, const int* in_sizes, int n_in,
                              void* d_out, int out_size, void* d_ws, size_t ws_size,
                              hipStream_t stream)
{
    const float* x   = (const float*)d_in[0];
    const float* Wq  = (const float*)d_in[1];
    const float* bq  = (const float*)d_in[2];
    const float* Wk  = (const float*)d_in[3];
    const float* bk  = (const float*)d_in[4];
    const float* Wv  = (const float*)d_in[5];
    const float* bv  = (const float*)d_in[6];
    const int* ei    = (const int*)d_in[7];
    const int* batch = (const int*)d_in[8];

    const int N = in_sizes[8];        // 50000
    const int E = in_sizes[7] / 2;    // 800000
    const int EP = E + 3 * N + 16;    // padded edge-slot capacity

    float*    q       = (float*)d_ws;
    float*    k       = q + (size_t)N * H;
    float*    v       = k + (size_t)N * H;
    float*    exps    = v + (size_t)N * H;
    unsigned* epack   = (unsigned*)(exps + EP);
    int*      counts  = (int*)(epack + EP);
    int*      offsets = counts + N;
    int*      cursor  = offsets + N;
    int*      bsum    = cursor + N;
    float*    denom   = (float*)(bsum + 64);

    hipMemsetAsync(counts, 0, N * sizeof(int), stream);
    hipMemsetAsync(denom, 0, NSEG * sizeof(float), stream);

    const int QB = (N + BM - 1) / BM;       // 1563 (covers E/512 hist chunks)
    const int NBSC = (N + SCB - 1) / SCB;   // 25 scan blocks

    qkv_hist<<<QB, 256, 0, stream>>>(
        x, Wq, bq, Wk, bk, Wv, bv, q, k, v, ei, counts, N, E);

    scanA<<<NBSC, 256, 0, stream>>>(counts, offsets, bsum, N);
    scanB<<<1, 64, 0, stream>>>(bsum, NBSC);
    scanC<<<NBSC, 256, 0, stream>>>(bsum, offsets, cursor, N);

    reorder_kernel<<<(E + 255) / 256, 256, 0, stream>>>(
        ei, batch, cursor, epack, E, N);

    score_kernel<<<2048, 256, 0, stream>>>(
        q, k, epack, offsets, counts, exps, denom, N);

    accum_kernel<<<(N + 3) / 4, 256, 0, stream>>>(
        v, exps, epack, offsets, counts, denom, (float*)d_out, N);
}